// Round 1
// baseline (208.981 us; speedup 1.0000x reference)
//
#include <hip/hip_runtime.h>

// CRF-RNN mean-field, 6 dispatches: whole-volume-per-block separable 3-D
// Gaussian convs in LDS + atomically pre-reduced message field.
//
// Previous plateau (11 dispatches, ~98 us) was launch-bound: VALUBusy 4.6%,
// Occupancy 8%, ~3.5 us exec + ~1.4 us dispatch per kernel; ~45 us of total
// is harness fill/restore. This removes 5 kernel boundaries:
//   k_pre   (9 blocks)  : build 9 pair fields from q=u, full 3-D conv each
//                         entirely in LDS, write raw zout + normS, zero the
//                         4 msg accumulators.
//   k_fused (6 blocks)x4: q-update (it==1: from raw zout + norm pairs,
//                         computing normB like the old it==0 path; it>=2:
//                         q = u - C*msg), scale by its pair coefficient,
//                         full 3-D conv, atomically accumulate the
//                         coefficient-weighted contribution into msg[it].
//   k_final (36 blocks) : q5 = u - C*msg4 -> out.
//
// Why this dodges R7/R11's measured load storms: the WRITER of each filtered
// pair knows its per-point read coefficient (Pt_k(i)*invf_k*inv_nb(i), resp.
// inv_ns(i)), so the 6 pairs are pre-reduced into ONE float2 msg field via
// fp32 global atomics; consumers read 73 KB (msg) + u + rgb, not 442 KB of
// per-pair planes per block. Zero-init race avoided with 4 separate msg
// generations, all zeroed in k_pre (no concurrent reader/writer).
//
// Conv engine: one channel field [24][24][17] floats in LDS (39 KB, x-stride
// 17 => odd-stride column reads are conflict-free). Line convs are register-
// tiled: in[]/out[] lines and the 24 Gaussian weights all in VGPRs with
// fully unrolled compile-time indices (rule: no runtime-indexed reg arrays),
// so inner loops are pure v_fma streams. Two channels run back-to-back
// through the same buffer (ch1 stashed in 18 VGPRs meanwhile).

#define DD 24
#define HH 24
#define WW 16
#define XS 17              // padded x-stride (floats)
#define YSTR (HH * XS)     // 408
#define NPTS 9216
#define NBLK 512
#define PPT 18             // points per thread (9216/512)
#define NT 5
#define LOG2E 1.4426950408889634f
#define K3L   (LOG2E / 18.0f)
#define K160L (LOG2E / 51200.0f)
#define EXP2  __builtin_amdgcn_exp2f

// lds index of flat point i (i = ((z*24)+y)*16 + x): 17*(i>>4) + (i&15)
#define LIDX(i) (XS * ((i) >> 4) + ((i) & 15))

// ---- register-tiled line-conv passes (in-place, 2 barriers each) --------
static __device__ __forceinline__ void pass_x(float* A, const float* w, int t) {
    float i0[WW], o0[WW], i1[WW], o1[WW];
    const int b0 = XS * t;
    const int b1 = XS * (NBLK + t);
    const bool two = (t < (DD * HH - NBLK));   // rows 512..575
#pragma unroll
    for (int xp = 0; xp < WW; ++xp) i0[xp] = A[b0 + xp];
    if (two) {
#pragma unroll
        for (int xp = 0; xp < WW; ++xp) i1[xp] = A[b1 + xp];
    }
#pragma unroll
    for (int x = 0; x < WW; ++x) {
        float a = 0.f;
#pragma unroll
        for (int xp = 0; xp < WW; ++xp)
            a = fmaf(w[x > xp ? x - xp : xp - x], i0[xp], a);
        o0[x] = a;
    }
    if (two) {
#pragma unroll
        for (int x = 0; x < WW; ++x) {
            float a = 0.f;
#pragma unroll
            for (int xp = 0; xp < WW; ++xp)
                a = fmaf(w[x > xp ? x - xp : xp - x], i1[xp], a);
            o1[x] = a;
        }
    }
    __syncthreads();
#pragma unroll
    for (int x = 0; x < WW; ++x) A[b0 + x] = o0[x];
    if (two) {
#pragma unroll
        for (int x = 0; x < WW; ++x) A[b1 + x] = o1[x];
    }
    __syncthreads();
}

static __device__ __forceinline__ void pass_y(float* A, const float* w, int t) {
    float in[HH], o[HH];
    const bool act = (t < DD * WW);            // 384 (z,x) columns
    const int base = (t >> 4) * YSTR + (t & 15);
    if (act) {
#pragma unroll
        for (int yp = 0; yp < HH; ++yp) in[yp] = A[base + XS * yp];
#pragma unroll
        for (int y = 0; y < HH; ++y) {
            float a = 0.f;
#pragma unroll
            for (int yp = 0; yp < HH; ++yp)
                a = fmaf(w[y > yp ? y - yp : yp - y], in[yp], a);
            o[y] = a;
        }
    }
    __syncthreads();
    if (act) {
#pragma unroll
        for (int y = 0; y < HH; ++y) A[base + XS * y] = o[y];
    }
    __syncthreads();
}

static __device__ __forceinline__ void pass_z(float* A, const float* w, int t) {
    float in[DD], o[DD];
    const bool act = (t < HH * WW);            // 384 (y,x) columns
    const int base = (t >> 4) * XS + (t & 15);
    if (act) {
#pragma unroll
        for (int zp = 0; zp < DD; ++zp) in[zp] = A[base + YSTR * zp];
#pragma unroll
        for (int z = 0; z < DD; ++z) {
            float a = 0.f;
#pragma unroll
            for (int zp = 0; zp < DD; ++zp)
                a = fmaf(w[z > zp ? z - zp : zp - z], in[zp], a);
            o[z] = a;
        }
    }
    __syncthreads();
    if (act) {
#pragma unroll
        for (int z = 0; z < DD; ++z) A[base + YSTR * z] = o[z];
    }
    __syncthreads();
}

static __device__ __forceinline__ void conv3(float* A, const float* w, int t) {
    pass_x(A, w, t);
    pass_y(A, w, t);
    pass_z(A, w, t);
}

// ---- pre: 9 full-volume pair convs from q=u; normS; zero msg gens -------
__global__ __launch_bounds__(NBLK, 2)
void k_pre(const float2* __restrict__ u2, const float* __restrict__ rgb,
           float2* __restrict__ zout, float* __restrict__ normS,
           float2* __restrict__ msgAll) {
    __shared__ float A[DD * YSTR];
    __shared__ float sxl[WW], syl[HH], szl[DD];
    const int p = blockIdx.x, t = threadIdx.x;
    const float kk = (p == 0) ? K3L : K160L;

    float w[24];
#pragma unroll
    for (int d = 0; d < 24; ++d) w[d] = EXP2(-(float)(d * d) * kk);

    // zero the 4 msg accumulator generations (nobody reads them this kernel)
    {
        int g = p * NBLK + t;
        for (int j = g; j < 4 * NPTS; j += 9 * NBLK)
            msgAll[j] = make_float2(0.f, 0.f);
    }

    if (p == 0) {   // per-coordinate 1-D norm sums (theta=3), 64 threads
        if (t < WW) {
            float s = 0.f;
            for (int xp = 0; xp < WW; ++xp) {
                float d = (float)(t - xp);
                s += EXP2(-d * d * K3L);
            }
            sxl[t] = s;
        } else if (t >= 64 && t < 64 + HH) {
            int y = t - 64; float s = 0.f;
            for (int yp = 0; yp < HH; ++yp) {
                float d = (float)(y - yp);
                s += EXP2(-d * d * K3L);
            }
            syl[y] = s;
        } else if (t >= 128 && t < 128 + DD) {
            int z = t - 128; float s = 0.f;
            for (int zp = 0; zp < DD; ++zp) {
                float d = (float)(z - zp);
                s += EXP2(-d * d * K3L);
            }
            szl[z] = s;
        }
    }

    float vy[PPT], f0[PPT];
#pragma unroll
    for (int k = 0; k < PPT; ++k) {
        const int i = t + k * NBLK;
        float2 v;
        if (p == 0) {
            v = u2[i];
        } else {
            const float I3 = rgb[i] * (1.f / 3.f);
            const float Pt0 = EXP2(-0.5f * LOG2E * I3 * I3);
            const float Pt1 = Pt0 * I3, Pt2 = Pt1 * I3, Pt3 = Pt2 * I3,
                        Pt4 = Pt3 * I3;
            if (p < 6) {
                const float P = (p == 1) ? Pt0 : (p == 2) ? Pt1 :
                                (p == 3) ? Pt2 : (p == 4) ? Pt3 : Pt4;
                float2 q = u2[i];
                v = make_float2(P * q.x, P * q.y);
            } else {
                const int j = p - 6;
                v = make_float2((j == 0) ? Pt0 : (j == 1) ? Pt2 : Pt4,
                                (j == 0) ? Pt1 : (j == 1) ? Pt3 : 0.f);
            }
        }
        A[LIDX(i)] = v.x;
        vy[k] = v.y;
    }
    __syncthreads();

    if (p == 0) {   // inverse spatial norm, closed form
#pragma unroll
        for (int k = 0; k < PPT; ++k) {
            const int i = t + k * NBLK;
            const int x = i & 15, rowid = i >> 4;
            const int y = rowid % HH, z = rowid / HH;
            normS[i] = 1.f / (sxl[x] * syl[y] * szl[z]);
        }
    }

    conv3(A, w, t);                       // channel 0
#pragma unroll
    for (int k = 0; k < PPT; ++k) f0[k] = A[LIDX(t + k * NBLK)];
    __syncthreads();
#pragma unroll
    for (int k = 0; k < PPT; ++k) A[LIDX(t + k * NBLK)] = vy[k];
    __syncthreads();
    conv3(A, w, t);                       // channel 1

#pragma unroll
    for (int k = 0; k < PPT; ++k) {
        const int i = t + k * NBLK;
        zout[p * NPTS + i] = make_float2(f0[k], A[LIDX(i)]);
    }
}

// ---- fused iteration: update -> scale -> 3-D conv -> atomic msg emit ----
__global__ __launch_bounds__(NBLK, 2)
void k_fused(const float2* __restrict__ zout, const float2* __restrict__ msgPrev,
             float2* __restrict__ msgNext, const float* __restrict__ rgb,
             const float2* __restrict__ u2, const float* __restrict__ sw,
             const float* __restrict__ bw, const float* __restrict__ compat,
             const float* __restrict__ normS, float* __restrict__ normB,
             int it) {
    __shared__ float A[DD * YSTR];
    const int p = blockIdx.x, t = threadIdx.x;
    const float kk = (p == 0) ? K3L : K160L;

    float w[24];
#pragma unroll
    for (int d = 0; d < 24; ++d) w[d] = EXP2(-(float)(d * d) * kk);

    const float c00 = compat[0], c01 = compat[1], c10 = compat[2], c11 = compat[3];
    const float sw0 = sw[0], sw1 = sw[1], bw0 = bw[0], bw1 = bw[1];

    float vy[PPT], cc[PPT], f0[PPT];
#pragma unroll
    for (int k = 0; k < PPT; ++k) {
        const int i = t + k * NBLK;
        const float I3 = rgb[i] * (1.f / 3.f);
        const float Pt0 = EXP2(-0.5f * LOG2E * I3 * I3);
        const float Pt1 = Pt0 * I3, Pt2 = Pt1 * I3, Pt3 = Pt2 * I3,
                    Pt4 = Pt3 * I3;
        float q0, q1, ccv;
        if (it == 1) {
            // raw-zout path: also derives + stores normB (old it==0 logic)
            float2 zs  = zout[i];
            float2 zb0 = zout[1 * NPTS + i], zb1 = zout[2 * NPTS + i];
            float2 zb2 = zout[3 * NPTS + i], zb3 = zout[4 * NPTS + i];
            float2 zb4 = zout[5 * NPTS + i];
            float2 n0  = zout[6 * NPTS + i], n1 = zout[7 * NPTS + i];
            float2 n2  = zout[8 * NPTS + i];
            const float nb = Pt0 * n0.x + Pt1 * n0.y + 0.5f * Pt2 * n1.x
                           + (1.f / 6.f) * Pt3 * n1.y + (1.f / 24.f) * Pt4 * n2.x;
            if (p == 0) normB[i] = nb;
            const float inv_nb = 1.f / nb;
            const float inv_ns = normS[i];
            float b0 = Pt0 * zb0.x + Pt1 * zb1.x + 0.5f * Pt2 * zb2.x
                     + (1.f / 6.f) * Pt3 * zb3.x + (1.f / 24.f) * Pt4 * zb4.x;
            float b1 = Pt0 * zb0.y + Pt1 * zb1.y + 0.5f * Pt2 * zb2.y
                     + (1.f / 6.f) * Pt3 * zb3.y + (1.f / 24.f) * Pt4 * zb4.y;
            b0 *= inv_nb; b1 *= inv_nb;
            const float s0 = zs.x * inv_ns, s1 = zs.y * inv_ns;
            const float m0 = s0 * sw0 + b0 * bw0;
            const float m1 = s1 * sw1 + b1 * bw1;
            const float2 uu = u2[i];
            q0 = uu.x - (c00 * m0 + c01 * m1);
            q1 = uu.y - (c10 * m0 + c11 * m1);
            ccv = (p == 0) ? inv_ns : inv_nb;
        } else {
            const float2 m = msgPrev[i];
            const float2 uu = u2[i];
            q0 = uu.x - (c00 * m.x + c01 * m.y);
            q1 = uu.y - (c10 * m.x + c11 * m.y);
            ccv = (p == 0) ? normS[i] : (1.f / normB[i]);
        }
        if (p == 0) {
            A[LIDX(i)] = q0; vy[k] = q1; cc[k] = ccv;
        } else {
            const float P = (p == 1) ? Pt0 : (p == 2) ? Pt1 :
                            (p == 3) ? Pt2 : (p == 4) ? Pt3 : Pt4;
            const float invfp = (p <= 2) ? 1.f : (p == 3) ? 0.5f :
                                (p == 4) ? (1.f / 6.f) : (1.f / 24.f);
            A[LIDX(i)] = P * q0; vy[k] = P * q1; cc[k] = ccv * P * invfp;
        }
    }
    __syncthreads();

    conv3(A, w, t);                       // channel 0
#pragma unroll
    for (int k = 0; k < PPT; ++k) f0[k] = A[LIDX(t + k * NBLK)];
    __syncthreads();
#pragma unroll
    for (int k = 0; k < PPT; ++k) A[LIDX(t + k * NBLK)] = vy[k];
    __syncthreads();
    conv3(A, w, t);                       // channel 1

    const float cw0 = (p == 0) ? sw0 : bw0;
    const float cw1 = (p == 0) ? sw1 : bw1;
#pragma unroll
    for (int k = 0; k < PPT; ++k) {
        const int i = t + k * NBLK;
        unsafeAtomicAdd(&msgNext[i].x, cc[k] * cw0 * f0[k]);
        unsafeAtomicAdd(&msgNext[i].y, cc[k] * cw1 * A[LIDX(i)]);
    }
}

// ---- final pointwise update -> out --------------------------------------
__global__ __launch_bounds__(256)
void k_final(const float2* __restrict__ msg, const float2* __restrict__ u2,
             const float* __restrict__ compat, float2* __restrict__ out) {
    const int i = blockIdx.x * 256 + threadIdx.x;
    const float c00 = compat[0], c01 = compat[1], c10 = compat[2], c11 = compat[3];
    const float2 m = msg[i];
    const float2 uu = u2[i];
    out[i] = make_float2(uu.x - (c00 * m.x + c01 * m.y),
                         uu.y - (c10 * m.x + c11 * m.y));
}

extern "C" void kernel_launch(void* const* d_in, const int* in_sizes, int n_in,
                              void* d_out, int out_size, void* d_ws, size_t ws_size,
                              hipStream_t stream) {
    const float2* u2     = (const float2*)d_in[0];
    const float*  rgb    = (const float*)d_in[1];
    const float*  sw     = (const float*)d_in[2];
    const float*  bw     = (const float*)d_in[3];
    const float*  compat = (const float*)d_in[4];
    float2* out = (float2*)d_out;

    float2* ws2    = (float2*)d_ws;
    float2* zout   = ws2;                       // 9 * NPTS float2 (raw gen-0)
    float2* msgAll = ws2 + 9 * NPTS;            // 4 * NPTS float2 (gens 1..4)
    float*  normS  = (float*)(ws2 + 13 * NPTS); // NPTS
    float*  normB  = normS + NPTS;              // NPTS

    k_pre<<<9, NBLK, 0, stream>>>(u2, rgb, zout, normS, msgAll);
    for (int it = 1; it <= 4; ++it) {
        const float2* mprev = (it >= 2) ? (msgAll + (size_t)(it - 2) * NPTS)
                                        : msgAll;   // unused at it==1
        k_fused<<<6, NBLK, 0, stream>>>(zout, mprev,
                                        msgAll + (size_t)(it - 1) * NPTS,
                                        rgb, u2, sw, bw, compat,
                                        normS, normB, it);
    }
    k_final<<<NPTS / 256, 256, 0, stream>>>(msgAll + 3 * NPTS, u2, compat, out);
}

// Round 2
// 97.506 us; speedup vs baseline: 2.1433x; 2.1433x over previous
//
#include <hip/hip_runtime.h>

// CRF-RNN mean-field, separable filters, field-PAIRED planes, 11 dispatches.
// Grid 24(z) x 24(y) x 16(x), N=9216, C=2, 5 iterations.
// == Best-measured variant (97.6-98.4 us). Restored after R1 fusion failure. ==
//
// Ks (theta=3) = Gz (x) Gy (x) Gx  -- exact separable 1-D convs.
// Kb = S160 * E_i E_j * exp(I3_i*I3_j), Taylor NT=5 (err ~1e-7).
// 6 iter PAIRS: pair0 = (q0,q1) theta=3; pair(1+t) = (P_t q0, P_t q1) th=160.
// 3 norm pairs (6..8): (P0,P1),(P2,P3),(P4,0) th=160, filtered once.
//
// Structure/iter: k_zconv (tmp2 -> zout2, one pair per block, no LDS) then
// k_xyupd (zout2 -> pointwise update (redundant per pair-block) -> xy-conv of
// pair p -> tmp2). Final iter: k_zconv + pointwise k_final.
//
// Session lessons (measured):
//  - R3/R10 (prev): persistent-kernel sync loses both ways (threadfence =
//    bulk L2 wb/inv ~19us/barrier; relaxed sc1 = uncached LLC trips).
//    Kernel boundaries + normal cached loads are the cheap coherence.
//  - R7/R11 (prev): one-kernel-per-iteration forces >=24x read redundancy
//    (82 / 20 us per kernel). 2 thin boundaries/iter + non-redundant reads win.
//  - R1 (this session): whole-volume-per-block fusion (6 dispatches, 6-9
//    blocks) = 209 us. 97% of GPU idle, 2 waves/SIMD dependent-FMA chains,
//    ~100 scalar ds_reads/thread unhidden, likely VGPR spills in the
//    register-tiled conv. Launch savings (7 us) << serialization (+100 us).
//    Lesson: fewer kernels only wins if each stays >=144 blocks wide.
//  - Floor accounting: ~45 us harness fill+restore + 11 x (~1.4 us dispatch
//    + ~3.5 us ramp/exec) = launch-bound plateau 97-104 us.

#define DD 24
#define HH 24
#define WW 16
#define SLICE 384
#define NPTS 9216
#define NT 5
#define NPAIR 6
#define NPTOT 9
#define LOG2E 1.4426950408889634f
#define K3L   (LOG2E / 18.0f)
#define K160L (LOG2E / 51200.0f)
#define EXP2  __builtin_amdgcn_exp2f

static __device__ __forceinline__ int iabs(int a) { return a < 0 ? -a : a; }

// ---- pre: xy conv of 9 pairs from q=u. grid (DD, 9) ---------------------
__global__ __launch_bounds__(SLICE)
void k_pre(const float2* __restrict__ u2, const float* __restrict__ rgb,
           float2* __restrict__ tmp2, float* __restrict__ normS) {
    __shared__ float gk[32];
    __shared__ float2 sA[HH][WW + 1];
    __shared__ float2 sB[HH][WW + 1];
    const int z = blockIdx.x, p = blockIdx.y, t = threadIdx.x;
    const int y = t >> 4, x = t & 15;
    const int i = z * SLICE + t;

    const float kk = (p == 0) ? K3L : K160L;
    if (t < DD) gk[t] = EXP2(-(float)(t * t) * kk);

    const float I3 = rgb[i] * (1.f / 3.f);
    float Pt[NT];
    Pt[0] = EXP2(-0.5f * LOG2E * I3 * I3);
#pragma unroll
    for (int k = 1; k < NT; ++k) Pt[k] = Pt[k - 1] * I3;

    float2 v;
    if (p == 0) {
        v = u2[i];
    } else if (p < NPAIR) {
        float2 q = u2[i];
        float P = Pt[p - 1];
        v = make_float2(P * q.x, P * q.y);
    } else {
        int j = p - NPAIR;
        v = make_float2(Pt[2 * j], (j < 2) ? Pt[2 * j + 1] : 0.f);
    }
    sA[y][x] = v;
    __syncthreads();

    float a0 = 0.f, a1 = 0.f;
#pragma unroll
    for (int xp = 0; xp < WW; ++xp) {
        float w = gk[iabs(x - xp)];
        float2 vv = sA[y][xp];
        a0 = fmaf(w, vv.x, a0);
        a1 = fmaf(w, vv.y, a1);
    }
    sB[y][x] = make_float2(a0, a1);
    __syncthreads();
    float b0 = 0.f, b1 = 0.f;
#pragma unroll
    for (int yp = 0; yp < HH; ++yp) {
        float w = gk[iabs(y - yp)];
        float2 vv = sB[yp][x];
        b0 = fmaf(w, vv.x, b0);
        b1 = fmaf(w, vv.y, b1);
    }
    tmp2[p * NPTS + i] = make_float2(b0, b1);

    if (p == 0) {
        // inverse spatial normalization, stored once (gk == g3 here)
        float sx = 0.f, sy = 0.f, sz = 0.f;
#pragma unroll
        for (int xp = 0; xp < WW; ++xp) sx += gk[iabs(x - xp)];
#pragma unroll
        for (int yp = 0; yp < HH; ++yp) sy += gk[iabs(y - yp)];
#pragma unroll
        for (int zp = 0; zp < DD; ++zp) sz += gk[iabs(z - zp)];
        normS[i] = 1.0f / (sx * sy * sz);
    }
}

// ---- z conv, ONE pair per block, no LDS. grid (DD, np) ------------------
__global__ __launch_bounds__(SLICE)
void k_zconv(const float2* __restrict__ tmp2, float2* __restrict__ zout2) {
    const int z = blockIdx.x, p = blockIdx.y, t = threadIdx.x;
    const float kk = (p == 0) ? K3L : K160L;
    float acc0 = 0.f, acc1 = 0.f;
    const float2* src = tmp2 + p * NPTS + t;
#pragma unroll 6
    for (int zp = 0; zp < DD; ++zp) {
        int d = z - zp;
        float w = EXP2(-(float)(d * d) * kk);
        float2 v = src[zp * SLICE];
        acc0 = fmaf(w, v.x, acc0);
        acc1 = fmaf(w, v.y, acc1);
    }
    zout2[p * NPTS + z * SLICE + t] = make_float2(acc0, acc1);
}

// ---- shared pointwise update ------------------------------------------
static __device__ __forceinline__ void mf_update(
        const float2 zp_[NPAIR], const float* Pt, float inv_ns, float inv_nb,
        const float* sw, const float* bw, const float* compat,
        const float2 uu, float* q0o, float* q1o) {
    const float invf[NT] = {1.f, 1.f, 0.5f, 1.f / 6.f, 1.f / 24.f};
    float b0 = 0.f, b1 = 0.f;
#pragma unroll
    for (int k = 0; k < NT; ++k) {
        float w = Pt[k] * invf[k];
        b0 = fmaf(w, zp_[1 + k].x, b0);
        b1 = fmaf(w, zp_[1 + k].y, b1);
    }
    b0 *= inv_nb;
    b1 *= inv_nb;
    float s0 = zp_[0].x * inv_ns;
    float s1 = zp_[0].y * inv_ns;
    float m0 = s0 * sw[0] + b0 * bw[0];
    float m1 = s1 * sw[1] + b1 * bw[1];
    float p0 = fmaf(compat[0], m0, compat[1] * m1);
    float p1 = fmaf(compat[2], m0, compat[3] * m1);
    *q0o = uu.x - p0;
    *q1o = uu.y - p1;
}

// ---- fused update + xy conv of pair p. grid (DD, 6) ---------------------
__global__ __launch_bounds__(SLICE)
void k_xyupd(const float2* __restrict__ zout2, const float* __restrict__ rgb,
             const float2* __restrict__ u2,
             const float* __restrict__ sw, const float* __restrict__ bw,
             const float* __restrict__ compat,
             const float* __restrict__ normS, float* __restrict__ normB,
             float2* __restrict__ tmp2, int it) {
    __shared__ float gk[32];
    __shared__ float2 sA[HH][WW + 1];
    __shared__ float2 sB[HH][WW + 1];
    const int z = blockIdx.x, p = blockIdx.y, t = threadIdx.x;
    const int y = t >> 4, x = t & 15;
    const int i = z * SLICE + t;

    const float kk = (p == 0) ? K3L : K160L;
    if (t < DD) gk[t] = EXP2(-(float)(t * t) * kk);

    float2 zp_[NPAIR];
#pragma unroll
    for (int k = 0; k < NPAIR; ++k) zp_[k] = zout2[k * NPTS + i];

    const float I3 = rgb[i] * (1.f / 3.f);
    float Pt[NT];
    Pt[0] = EXP2(-0.5f * LOG2E * I3 * I3);
#pragma unroll
    for (int k = 1; k < NT; ++k) Pt[k] = Pt[k - 1] * I3;

    float inv_nb;
    if (it == 0) {
        float2 n0 = zout2[6 * NPTS + i];
        float2 n1 = zout2[7 * NPTS + i];
        float2 n2 = zout2[8 * NPTS + i];
        float nb = Pt[0] * n0.x + Pt[1] * n0.y + 0.5f * Pt[2] * n1.x
                 + (1.f / 6.f) * Pt[3] * n1.y + (1.f / 24.f) * Pt[4] * n2.x;
        if (p == 0) normB[i] = nb;
        inv_nb = 1.0f / nb;
    } else {
        inv_nb = 1.0f / normB[i];
    }

    float q0, q1;
    mf_update(zp_, Pt, normS[i], inv_nb, sw, bw, compat, u2[i], &q0, &q1);

    float2 v;
    if (p == 0) v = make_float2(q0, q1);
    else { float P = Pt[p - 1]; v = make_float2(P * q0, P * q1); }

    sA[y][x] = v;
    __syncthreads();
    float a0 = 0.f, a1 = 0.f;
#pragma unroll
    for (int xp = 0; xp < WW; ++xp) {
        float w = gk[iabs(x - xp)];
        float2 vv = sA[y][xp];
        a0 = fmaf(w, vv.x, a0);
        a1 = fmaf(w, vv.y, a1);
    }
    sB[y][x] = make_float2(a0, a1);
    __syncthreads();
    float b0 = 0.f, b1 = 0.f;
#pragma unroll
    for (int yp = 0; yp < HH; ++yp) {
        float w = gk[iabs(y - yp)];
        float2 vv = sB[yp][x];
        b0 = fmaf(w, vv.x, b0);
        b1 = fmaf(w, vv.y, b1);
    }
    tmp2[p * NPTS + i] = make_float2(b0, b1);
}

// ---- final pointwise update -> out. grid 36 x 256, no LDS ---------------
__global__ __launch_bounds__(256)
void k_final(const float2* __restrict__ zout2, const float* __restrict__ rgb,
             const float2* __restrict__ u2,
             const float* __restrict__ sw, const float* __restrict__ bw,
             const float* __restrict__ compat,
             const float* __restrict__ normS, const float* __restrict__ normB,
             float2* __restrict__ out) {
    const int i = blockIdx.x * 256 + threadIdx.x;

    float2 zp_[NPAIR];
#pragma unroll
    for (int k = 0; k < NPAIR; ++k) zp_[k] = zout2[k * NPTS + i];

    const float I3 = rgb[i] * (1.f / 3.f);
    float Pt[NT];
    Pt[0] = EXP2(-0.5f * LOG2E * I3 * I3);
#pragma unroll
    for (int k = 1; k < NT; ++k) Pt[k] = Pt[k - 1] * I3;

    float q0, q1;
    mf_update(zp_, Pt, normS[i], 1.0f / normB[i], sw, bw, compat,
              u2[i], &q0, &q1);
    out[i] = make_float2(q0, q1);
}

extern "C" void kernel_launch(void* const* d_in, const int* in_sizes, int n_in,
                              void* d_out, int out_size, void* d_ws, size_t ws_size,
                              hipStream_t stream) {
    const float2* u2     = (const float2*)d_in[0];
    const float*  rgb    = (const float*)d_in[1];
    const float*  sw     = (const float*)d_in[2];
    const float*  bw     = (const float*)d_in[3];
    const float*  compat = (const float*)d_in[4];
    float2* out = (float2*)d_out;

    float2* ws2   = (float2*)d_ws;
    float2* tmp2  = ws2;                        // NPTOT*NPTS float2
    float2* zout2 = ws2 + NPTOT * NPTS;         // NPTOT*NPTS float2
    float*  normS = (float*)(ws2 + 2 * NPTOT * NPTS);   // NPTS
    float*  normB = normS + NPTS;                        // NPTS

    k_pre<<<dim3(DD, NPTOT), SLICE, 0, stream>>>(u2, rgb, tmp2, normS);

    for (int it = 0; it < 5; ++it) {
        k_zconv<<<dim3(DD, it == 0 ? NPTOT : NPAIR), SLICE, 0, stream>>>(tmp2, zout2);
        if (it < 4)
            k_xyupd<<<dim3(DD, NPAIR), SLICE, 0, stream>>>(zout2, rgb, u2, sw, bw,
                                                           compat, normS, normB,
                                                           tmp2, it);
        else
            k_final<<<NPTS / 256, 256, 0, stream>>>(zout2, rgb, u2, sw, bw,
                                                    compat, normS, normB, out);
    }
}